// Round 20
// baseline (12958.760 us; speedup 1.0000x reference)
//
#include <hip/hip_runtime.h>
#include <hip/hip_bf16.h>

#define B_TOT 2048
#define NTS   200
#define DIN   128
#define LATN  256
#define ROWS  16
#define NBLK  (B_TOT/ROWS)   // 128
#define NTHR  1024           // 16 waves, 4/SIMD

#define CATP  648
#define HURP  1032

// ws layout (BYTES), identical to R16. fp8 gates in 512-B tiles; n1,n2 f16 1-KB tiles.
#define OFF8_O1   0          // 256x256 fp8
#define OFF8_O2   65536      // 256x256 fp8
#define OFF8_UR1  131072     // 640x1024 fp8
#define OFF8_UR2  786432     // 512x512 fp8
#define OFF16_N1  1048576    // 640x512 f16
#define OFF16_N2  1703936    // 512x512 f16
#define OFF_SC    2228224    // float[2048] per-column scales

typedef __attribute__((ext_vector_type(8))) _Float16 h8v;
typedef __attribute__((ext_vector_type(2))) __fp16   q2v;
typedef __attribute__((ext_vector_type(2))) float    f2v;
typedef __attribute__((ext_vector_type(4))) float    f4v;

__device__ __forceinline__ unsigned short f2h(float x) {
    _Float16 h = (_Float16)x;
    unsigned short u;
    __builtin_memcpy(&u, &h, 2);
    return u;
}

__device__ __forceinline__ float fast_tanh(float x) {
    float e = __expf(2.f * x);
    return 1.f - 2.f * __builtin_amdgcn_rcpf(e + 1.f);
}
__device__ __forceinline__ float fast_sig(float x) {
    return __builtin_amdgcn_rcpf(1.f + __expf(-x));
}

__device__ __forceinline__ h8v dec8(uint2 b) {
    f2v p0 = __builtin_amdgcn_cvt_pk_f32_fp8(b.x, false);
    f2v p1 = __builtin_amdgcn_cvt_pk_f32_fp8(b.x, true);
    f2v p2 = __builtin_amdgcn_cvt_pk_f32_fp8(b.y, false);
    f2v p3 = __builtin_amdgcn_cvt_pk_f32_fp8(b.y, true);
    union { h8v h; q2v q[4]; } u;
    u.q[0] = __builtin_amdgcn_cvt_pkrtz(p0.x, p0.y);
    u.q[1] = __builtin_amdgcn_cvt_pkrtz(p1.x, p1.y);
    u.q[2] = __builtin_amdgcn_cvt_pkrtz(p2.x, p2.y);
    u.q[3] = __builtin_amdgcn_cvt_pkrtz(p3.x, p3.y);
    return u.h;
}

// fp8 gate, depth-D circular register prefetch (fp8 B = uint2 = 2 VGPR/frag ->
// depth-4 fits the 64-VGPR budget at 1024 threads). k-chunk rotation as R11.
// bp includes lane*8; tile stride 512 B per (f, chunk).
template<int K, int NFR, int D>
__device__ __forceinline__ void mmloop8(const unsigned short* A, int strideA,
                                        const unsigned char* bp, int rot,
                                        f4v* acc, int arow, int ah)
{
    constexpr int NS = K / 32;
    constexpr int DD = (D < NS) ? D : NS;
    const unsigned short* ap = A + arow * strideA + ah * 8;
    uint2 bb[DD][NFR];
    h8v ab[DD];
#pragma unroll
    for (int d = 0; d < DD; ++d) {
        int c = rot + d; if (c >= NS) c -= NS;
        ab[d] = *(const h8v*)(ap + c * 32);
#pragma unroll
        for (int f = 0; f < NFR; ++f)
            bb[d][f] = *(const uint2*)(bp + (f * NS + c) * 512);
    }
#pragma unroll
    for (int s = 0; s < NS; ++s) {
        const int slot = s % DD;
#pragma unroll
        for (int f = 0; f < NFR; ++f)
            acc[f] = __builtin_amdgcn_mfma_f32_16x16x32_f16(ab[slot], dec8(bb[slot][f]), acc[f], 0, 0, 0);
        if (s + DD < NS) {
            int c = rot + s + DD; if (c >= NS) c -= NS;
            ab[slot] = *(const h8v*)(ap + c * 32);
#pragma unroll
            for (int f = 0; f < NFR; ++f)
                bb[slot][f] = *(const uint2*)(bp + (f * NS + c) * 512);
        }
    }
}

// f16 gate (n1, n2), depth-2 (R16-proven). bp16 in SHORT units, 512-short tiles.
template<int K, int NFR>
__device__ __forceinline__ void mmloop16(const unsigned short* A, int strideA,
                                         const unsigned short* bp16, int rot,
                                         f4v* acc, int arow, int ah)
{
    constexpr int NS = K / 32;
    const unsigned short* ap = A + arow * strideA + ah * 8;
    h8v bcur[NFR], bnxt[NFR];
    h8v acur, anxt;
    int c = rot;
    acur = *(const h8v*)(ap + c * 32);
#pragma unroll
    for (int f = 0; f < NFR; ++f) bcur[f] = *(const h8v*)(bp16 + f * NS * 512 + c * 512);
#pragma unroll 2
    for (int s = 0; s < NS; ++s) {
        int cn = c + 1; if (cn >= NS) cn = 0;
        if (s + 1 < NS) {
            anxt = *(const h8v*)(ap + cn * 32);
#pragma unroll
            for (int f = 0; f < NFR; ++f)
                bnxt[f] = *(const h8v*)(bp16 + f * NS * 512 + cn * 512);
        }
#pragma unroll
        for (int f = 0; f < NFR; ++f)
            acc[f] = __builtin_amdgcn_mfma_f32_16x16x32_f16(acur, bcur[f], acc[f], 0, 0, 0);
        if (s + 1 < NS) {
            acur = anxt;
#pragma unroll
            for (int f = 0; f < NFR; ++f) bcur[f] = bnxt[f];
        }
        c = cn;
    }
}

// ---------------- prep kernels (identical to R16) ----------------
__global__ void prep_fp8(const float* __restrict__ Wo1, const float* __restrict__ Wo2,
                         const float* __restrict__ Wu1, const float* __restrict__ Wr1,
                         const float* __restrict__ Wu2, const float* __restrict__ Wr2,
                         unsigned char* __restrict__ ws8, float* __restrict__ scg)
{
    int gwid = (blockIdx.x * blockDim.x + threadIdx.x) >> 6;
    int lane = threadIdx.x & 63;
    if (gwid >= 2048) return;
    const float* src; int K, N, scol, off8, scb, col;
    if (gwid < 256)       { col = gwid;        K = 256; N = 256; src = Wo1; scol = col; off8 = OFF8_O1;  scb = 0; }
    else if (gwid < 512)  { col = gwid - 256;  K = 256; N = 256; src = Wo2; scol = col; off8 = OFF8_O2;  scb = 256; }
    else if (gwid < 1536) { col = gwid - 512;  K = 640; N = 512; src = (col < 512) ? Wu1 : Wr1; scol = col & 511; off8 = OFF8_UR1; scb = 512; }
    else                  { col = gwid - 1536; K = 512; N = 256; src = (col < 256) ? Wu2 : Wr2; scol = col & 255; off8 = OFF8_UR2; scb = 1536; }
    float amax = 0.f;
    for (int k = lane; k < K; k += 64)
        amax = fmaxf(amax, fabsf(src[k * N + scol]));
#pragma unroll
    for (int m = 32; m >= 1; m >>= 1)
        amax = fmaxf(amax, __shfl_xor(amax, m, 64));
    const float inv = (amax > 0.f) ? 240.f / amax : 0.f;
    const int NS = K / 32;
    const int cb = col >> 4, lcol = col & 15;
    for (int k = lane; k < K; k += 64) {
        float v = src[k * N + scol] * inv;
        unsigned byte = (unsigned)__builtin_amdgcn_cvt_pk_fp8_f32(v, v, 0, false) & 0xffu;
        int s = k >> 5, kk = k & 31;
        int l8 = ((kk >> 3) << 4) | lcol;
        ws8[off8 + cb * (NS * 512) + s * 512 + l8 * 8 + (kk & 7)] = (unsigned char)byte;
    }
    if (lane == 0) scg[scb + col] = (amax > 0.f) ? amax / 240.f : 0.f;
}

__device__ __forceinline__ void tile_decode(int e, int K, int& col, int& k) {
    const int NS = K / 32;
    int cb  = e / (NS * 512);
    int rem = e - cb * (NS * 512);
    int s   = rem >> 9;
    int q   = rem & 511;
    int l   = q >> 3;
    int j   = q & 7;
    col = cb * 16 + (l & 15);
    k   = s * 32 + (l >> 4) * 8 + j;
}

__global__ void prep_n16(const float* __restrict__ Wn1, const float* __restrict__ Wn2,
                         unsigned short* __restrict__ ws16)
{
    int e = blockIdx.x * 256 + threadIdx.x;
    if (e >= 589824) return;
    int col, k;
    if (e < 327680) {
        tile_decode(e, 640, col, k);
        ws16[e] = f2h(Wn1[k * 512 + col]);
    } else {
        int e2 = e - 327680;
        tile_decode(e2, 512, col, k);
        ws16[e] = f2h(Wn2[k * 512 + col]);
    }
}

// ---------------- main persistent kernel ----------------
__launch_bounds__(NTHR)
__global__ void odernn_main(const float* __restrict__ data, const float* __restrict__ tsg,
                            const float* __restrict__ bu1, const float* __restrict__ bu2,
                            const float* __restrict__ br1, const float* __restrict__ br2,
                            const float* __restrict__ bn1, const float* __restrict__ bn2,
                            const float* __restrict__ bo1, const float* __restrict__ bo2,
                            const float* __restrict__ Wt1, const float* __restrict__ bt1,
                            const float* __restrict__ Wt2, const float* __restrict__ bt2,
                            const unsigned char* __restrict__ Wb,
                            float* __restrict__ out)
{
    __shared__ unsigned short cat[ROWS][CATP];   // f16: y|s|x; later c2|x
    __shared__ unsigned short hur[ROWS][HURP];   // f16: h_o / hu|hr / hn
    __shared__ float yf [ROWS][LATN];
    __shared__ float sf [ROWS][LATN];
    __shared__ float yof[ROWS][LATN];
    __shared__ float uf [ROWS][LATN];
    __shared__ float z1s[ROWS][100];
    __shared__ float msum[2][ROWS];
    __shared__ float bL[3072];                   // biases
    __shared__ float scL[2048];                  // per-column fp8 scales

    const unsigned short* W16n1 = (const unsigned short*)(Wb + OFF16_N1);
    const unsigned short* W16n2 = (const unsigned short*)(Wb + OFF16_N2);
    const float* scg = (const float*)(Wb + OFF_SC);

    const int tid  = threadIdx.x;
    const int lane = tid & 63;
    const int w    = tid >> 6;       // wave 0..15
    const int arow = lane & 15;
    const int ah   = lane >> 4;
    const int r0   = blockIdx.x * ROWS;
    const int rot  = (blockIdx.x >> 3) & 15;     // distinct per XCD-sharing block
    const int rot8 = rot & 7;

    for (int i = tid; i < ROWS * LATN; i += NTHR) {
        yf[i >> 8][i & 255] = 0.f;
        sf[i >> 8][i & 255] = 0.f;
    }
    for (int i = tid; i < ROWS * 512; i += NTHR)
        cat[i >> 9][i & 511] = 0;
    for (int i = tid; i < 3072; i += NTHR) {
        float v;
        if      (i <  256) v = bo1[i];
        else if (i <  512) v = bo2[i - 256];
        else if (i < 1024) v = bu1[i - 512];
        else if (i < 1536) v = br1[i - 1024];
        else if (i < 1792) v = bu2[i - 1536];
        else if (i < 2048) v = br2[i - 1792];
        else if (i < 2560) v = bn1[i - 2048];
        else               v = bn2[i - 2560];
        bL[i] = v;
    }
    for (int i = tid; i < 2048; i += NTHR)
        scL[i] = scg[i];
    const int xc = lane * 2;
    {
        const float2 xv = *(const float2*)(data + ((size_t)(r0 + w) * NTS + 199) * DIN + xc);
        cat[w][512 + xc + 0] = f2h(xv.x);
        cat[w][512 + xc + 1] = f2h(xv.y);
        float mp = (xc >= 64) ? (xv.x + xv.y) : 0.f;
#pragma unroll
        for (int m = 32; m >= 1; m >>= 1) mp += __shfl_xor(mp, m, 64);
        if (lane == 0) msum[0][w] = mp;
    }
    __syncthreads();

    for (int t = 0; t < NTS; ++t) {
        const float dtv = (t == 0) ? -0.01f : (tsg[199 - t] - tsg[200 - t]);

        // ---- G_o1 (fp8, d4): h_o = tanh(y @ Wo1 + bo1); cols [w*16,+16), NS=8 ----
        {
            f4v a[1] = {{0.f, 0.f, 0.f, 0.f}};
            mmloop8<256, 1, 4>(&cat[0][0], CATP, Wb + OFF8_O1 + w * 8 * 512 + lane * 8, rot8, a, arow, ah);
            const float sc = scL[w * 16 + arow], b = bL[w * 16 + arow];
#pragma unroll
            for (int i = 0; i < 4; ++i) {
                int row = ah * 4 + i, col = w * 16 + arow;
                hur[row][col] = f2h(fast_tanh(a[0][i] * sc + b));
            }
        }
        __syncthreads();

        // ---- G_o2 (fp8, d4): y_ode = y + (h_o @ Wo2 + bo2)*dt ----
        {
            f4v a[1] = {{0.f, 0.f, 0.f, 0.f}};
            mmloop8<256, 1, 4>(&hur[0][0], HURP, Wb + OFF8_O2 + w * 8 * 512 + lane * 8, rot8, a, arow, ah);
            const float sc = scL[256 + w * 16 + arow], b = bL[256 + w * 16 + arow];
#pragma unroll
            for (int i = 0; i < 4; ++i) {
                int row = ah * 4 + i, col = w * 16 + arow;
                float yo = yf[row][col] + (a[0][i] * sc + b) * dtv;
                yof[row][col] = yo;
                cat[row][col] = f2h(yo);
            }
        }
        __syncthreads();

        // ---- G_ur1 (fp8, d4): [hu|hr], 2 passes x 32 cols, NS=20 ----
#pragma unroll 1
        for (int p = 0; p < 2; ++p) {
            f4v a[2] = {{0.f, 0.f, 0.f, 0.f}, {0.f, 0.f, 0.f, 0.f}};
            mmloop8<640, 2, 4>(&cat[0][0], CATP,
                               Wb + OFF8_UR1 + (w * 4 + p * 2) * 20 * 512 + lane * 8, rot, a, arow, ah);
#pragma unroll
            for (int f = 0; f < 2; ++f) {
                int col = w * 64 + p * 32 + f * 16 + arow;
                const float sc = scL[512 + col], b = bL[512 + col];
#pragma unroll
                for (int i = 0; i < 4; ++i) {
                    int row = ah * 4 + i;
                    hur[row][col] = f2h(fast_tanh(a[f][i] * sc + b));
                }
            }
        }
        __syncthreads();

        // ---- G_ur2 (fp8, d4) + fused c2: u (waves 0-7), r -> c2 (waves 8-15); NS=16 ----
        {
            f4v a[2] = {{0.f, 0.f, 0.f, 0.f}, {0.f, 0.f, 0.f, 0.f}};
            const int c0 = w * 32;
            const int aoff = (w < 8) ? 0 : 512;
            mmloop8<512, 2, 4>(&hur[0][0] + aoff, HURP,
                               Wb + OFF8_UR2 + (w * 2) * 16 * 512 + lane * 8, rot, a, arow, ah);
#pragma unroll
            for (int f = 0; f < 2; ++f) {
                int j = c0 + f * 16 + arow;
                const float sc = scL[1536 + j], b = bL[1536 + j];
#pragma unroll
                for (int i = 0; i < 4; ++i) {
                    int row = ah * 4 + i;
                    float sg = fast_sig(a[f][i] * sc + b);
                    if (j < 256) {
                        uf[row][j] = sg;
                    } else {
                        int c = j - 256;
                        float yo = yof[row][c], so = sf[row][c];
                        cat[row][c]       = f2h(yo * sg);
                        cat[row][256 + c] = f2h(so * sg);
                    }
                }
            }
        }
        __syncthreads();

        // ---- G_n1 (f16, d2): hn = tanh(c2 @ Wn1 + bn1); cols [w*32,+32), NS=20 ----
        float2 xv;
        const bool hasx = (t + 1 < NTS);
        if (hasx)
            xv = *(const float2*)(data + ((size_t)(r0 + w) * NTS + (198 - t)) * DIN + xc);
        {
            f4v a[2];
#pragma unroll
            for (int f = 0; f < 2; ++f) {
                float b = bL[2048 + w * 32 + f * 16 + arow];
                a[f] = (f4v){b, b, b, b};
            }
            mmloop16<640, 2>(&cat[0][0], CATP, W16n1 + (w * 2) * 20 * 512 + lane * 8, rot, a, arow, ah);
#pragma unroll
            for (int f = 0; f < 2; ++f)
#pragma unroll
                for (int i = 0; i < 4; ++i) {
                    int row = ah * 4 + i, col = w * 32 + f * 16 + arow;
                    hur[row][col] = f2h(fast_tanh(a[f][i]));
                }
        }
        __syncthreads();

        // ---- G_n2 (f16, d2): ns = hn @ Wn2 + bn2 ; state update; write x_{t+1} ----
        {
            f4v a[2];
#pragma unroll
            for (int f = 0; f < 2; ++f) {
                float b = bL[2560 + w * 32 + f * 16 + arow];
                a[f] = (f4v){b, b, b, b};
            }
            mmloop16<512, 2>(&hur[0][0], HURP, W16n2 + (w * 2) * 16 * 512 + lane * 8, rot, a, arow, ah);
#pragma unroll
            for (int f = 0; f < 2; ++f)
#pragma unroll
                for (int i = 0; i < 4; ++i) {
                    int row = ah * 4 + i, j = w * 32 + f * 16 + arow;
                    float val = a[f][i];
                    bool m = msum[t & 1][row] > 0.f;
                    if (j < 256) {
                        float u  = uf[row][j];
                        float yo = yof[row][j];
                        float ny = (1.f - u) * val + u * yo;
                        float yn = m ? ny : yo;
                        yf[row][j] = yn;
                        cat[row][j] = f2h(yn);
                    } else {
                        int c = j - 256;
                        float u  = uf[row][c];
                        float so = sf[row][c];
                        float nstd = (1.f - u) * fabsf(val) + u * so;
                        float sn = m ? nstd : so;
                        sn = fabsf(sn);
                        sf[row][c] = sn;
                        cat[row][256 + c] = f2h(sn);
                    }
                }
        }
        if (hasx) {
            cat[w][512 + xc + 0] = f2h(xv.x);
            cat[w][512 + xc + 1] = f2h(xv.y);
            float mp = (xc >= 64) ? (xv.x + xv.y) : 0.f;
#pragma unroll
            for (int m = 32; m >= 1; m >>= 1) mp += __shfl_xor(mp, m, 64);
            if (lane == 0) msum[(t + 1) & 1][w] = mp;
        }
        __syncthreads();
    }

    // ---- final head (fp32, once): z = tanh([y|s]@Wt1+bt1)@Wt2+bt2 ----
    for (int it = tid; it < ROWS * 100; it += NTHR) {
        int r = it / 100, j = it - r * 100;
        float acc = bt1[j];
        for (int k = 0; k < 256; ++k) acc += yf[r][k] * Wt1[k * 100 + j];
        for (int k = 0; k < 256; ++k) acc += sf[r][k] * Wt1[(256 + k) * 100 + j];
        z1s[r][j] = fast_tanh(acc);
    }
    __syncthreads();
    for (int it = tid; it < ROWS * 512; it += NTHR) {
        int r = it >> 9, j = it & 511;
        float acc = bt2[j];
        for (int k = 0; k < 100; ++k) acc += z1s[r][k] * Wt2[k * 512 + j];
        int bg = r0 + r;
        if (j < 256) {
            out[(size_t)bg * 256 + j] = acc;
        } else {
            float v = fabsf(acc);
            if (v < 1e-20f) v = 1e-20f;
            out[(size_t)B_TOT * 256 + (size_t)bg * 256 + (j - 256)] = v;
        }
    }
}

extern "C" void kernel_launch(void* const* d_in, const int* in_sizes, int n_in,
                              void* d_out, int out_size, void* d_ws, size_t ws_size,
                              hipStream_t stream) {
    const float* data = (const float*)d_in[0];
    const float* ts   = (const float*)d_in[1];
    const float* Wu1  = (const float*)d_in[2];
    const float* bu1  = (const float*)d_in[3];
    const float* Wu2  = (const float*)d_in[4];
    const float* bu2  = (const float*)d_in[5];
    const float* Wr1  = (const float*)d_in[6];
    const float* br1  = (const float*)d_in[7];
    const float* Wr2  = (const float*)d_in[8];
    const float* br2  = (const float*)d_in[9];
    const float* Wn1  = (const float*)d_in[10];
    const float* bn1  = (const float*)d_in[11];
    const float* Wn2  = (const float*)d_in[12];
    const float* bn2  = (const float*)d_in[13];
    const float* Wo1  = (const float*)d_in[14];
    const float* bo1  = (const float*)d_in[15];
    const float* Wo2  = (const float*)d_in[16];
    const float* bo2  = (const float*)d_in[17];
    const float* Wt1  = (const float*)d_in[18];
    const float* bt1  = (const float*)d_in[19];
    const float* Wt2  = (const float*)d_in[20];
    const float* bt2  = (const float*)d_in[21];
    unsigned char* ws8 = (unsigned char*)d_ws;
    float* scg = (float*)(ws8 + OFF_SC);
    unsigned short* ws16 = (unsigned short*)(ws8 + OFF16_N1);
    float* out = (float*)d_out;

    prep_fp8<<<512, 256, 0, stream>>>(Wo1, Wo2, Wu1, Wr1, Wu2, Wr2, ws8, scg);
    prep_n16<<<2304, 256, 0, stream>>>(Wn1, Wn2, ws16);
    odernn_main<<<NBLK, NTHR, 0, stream>>>(
        data, ts, bu1, bu2, br1, br2, bn1, bn2, bo1, bo2,
        Wt1, bt1, Wt2, bt2, ws8, out);
}

// Round 21
// 5348.331 us; speedup vs baseline: 2.4230x; 2.4230x over previous
//
#include <hip/hip_runtime.h>
#include <hip/hip_bf16.h>

#define B_TOT 2048
#define NTS   200
#define DIN   128
#define LATN  256
#define ROWS  16
#define NBLK  (B_TOT/ROWS)   // 128
#define NTHR  1024           // 16 waves, 4/SIMD

#define CATP  648
#define HURP  1032

// ws offsets in bf16 elements. Each gate stored as MFMA-ready 1KB tiles:
// tile(cb, s) holds cols [cb*16, cb*16+16) x k [s*32, s*32+32);
// element (lane l, j) = W[k = s*32 + (l>>4)*8 + j][col = cb*16 + (l&15)].
// A wave's B-fragment load = 64 lanes x 16B contiguous = one 1KB burst.
#define OFF_WO1   0          // N=256  K=256
#define OFF_WO2   65536      // N=256  K=256
#define OFF_WUR1  131072     // N=1024 K=640
#define OFF_WUR2  786432     // N=512  K=512
#define OFF_WN1   1048576    // N=512  K=640
#define OFF_WN2   1376256    // N=512  K=512
#define WS_ELEMS  1638400

typedef __attribute__((ext_vector_type(8))) short s8v;
typedef __attribute__((ext_vector_type(4))) float f4v;

__device__ __forceinline__ unsigned short f2bf(float x) {
    __hip_bfloat16 h = __float2bfloat16(x);
    unsigned short u;
    __builtin_memcpy(&u, &h, 2);
    return u;
}

// Clamp-free: exp overflow -> inf -> rcp -> 0 saturates correctly.
__device__ __forceinline__ float fast_tanh(float x) {
    float e = __expf(2.f * x);
    return 1.f - 2.f * __builtin_amdgcn_rcpf(e + 1.f);
}
__device__ __forceinline__ float fast_sig(float x) {
    return __builtin_amdgcn_rcpf(1.f + __expf(-x));
}

// acc[f] += A[16,K] @ W-tile slice, k-chunk order ROTATED by block-uniform
// rot in [0,NS): breaks the cross-block lockstep so 16 blocks on an XCD hit
// 16 DIFFERENT L2 lines at any instant instead of serializing on one tile.
template<int K, int NFR>
__device__ __forceinline__ void mmloop(const unsigned short* A, int strideA,
                                       const unsigned short* bp, int rot,
                                       f4v* acc, int arow, int ah)
{
    constexpr int NS = K / 32;
    const unsigned short* ap = A + arow * strideA + ah * 8;
    s8v bcur[NFR], bnxt[NFR];
    s8v acur, anxt;
    int c = rot;                       // current chunk index (block-uniform)
    acur = *(const s8v*)(ap + c * 32);
#pragma unroll
    for (int f = 0; f < NFR; ++f) bcur[f] = *(const s8v*)(bp + f * NS * 512 + c * 512);
#pragma unroll 2
    for (int s = 0; s < NS; ++s) {
        int cn = c + 1; if (cn >= NS) cn = 0;
        if (s + 1 < NS) {
            anxt = *(const s8v*)(ap + cn * 32);
#pragma unroll
            for (int f = 0; f < NFR; ++f)
                bnxt[f] = *(const s8v*)(bp + f * NS * 512 + cn * 512);
        }
#pragma unroll
        for (int f = 0; f < NFR; ++f)
            acc[f] = __builtin_amdgcn_mfma_f32_16x16x32_bf16(acur, bcur[f], acc[f], 0, 0, 0);
        if (s + 1 < NS) {
            acur = anxt;
#pragma unroll
            for (int f = 0; f < NFR; ++f) bcur[f] = bnxt[f];
        }
        c = cn;
    }
}

// ---------------- weight prep: fp32 [K][N] -> bf16 MFMA-ready tiles ----------------
__device__ __forceinline__ void tile_decode(int e, int K, int& col, int& k) {
    const int NS = K / 32;
    int cb  = e / (NS * 512);
    int rem = e - cb * (NS * 512);
    int s   = rem >> 9;
    int q   = rem & 511;
    int l   = q >> 3;
    int j   = q & 7;
    col = cb * 16 + (l & 15);
    k   = s * 32 + (l >> 4) * 8 + j;
}

__global__ void prep_weights(const float* __restrict__ Wu1, const float* __restrict__ Wr1,
                             const float* __restrict__ Wu2, const float* __restrict__ Wr2,
                             const float* __restrict__ Wn1, const float* __restrict__ Wn2,
                             const float* __restrict__ Wo1, const float* __restrict__ Wo2,
                             unsigned short* __restrict__ ws)
{
    int idx = blockIdx.x * 256 + threadIdx.x;
    if (idx >= WS_ELEMS) return;
    float v;
    int col, k;
    if (idx < OFF_WO2) {
        tile_decode(idx - OFF_WO1, 256, col, k);
        v = Wo1[k * 256 + col];
    } else if (idx < OFF_WUR1) {
        tile_decode(idx - OFF_WO2, 256, col, k);
        v = Wo2[k * 256 + col];
    } else if (idx < OFF_WUR2) {
        tile_decode(idx - OFF_WUR1, 640, col, k);
        v = (col < 512) ? Wu1[k * 512 + col] : Wr1[k * 512 + (col - 512)];
    } else if (idx < OFF_WN1) {
        tile_decode(idx - OFF_WUR2, 512, col, k);
        v = (col < 256) ? Wu2[k * 256 + col] : Wr2[k * 256 + (col - 256)];
    } else if (idx < OFF_WN2) {
        tile_decode(idx - OFF_WN1, 640, col, k);
        v = Wn1[k * 512 + col];
    } else {
        tile_decode(idx - OFF_WN2, 512, col, k);
        v = Wn2[k * 512 + col];
    }
    ws[idx] = f2bf(v);
}

// ---------------- main persistent kernel ----------------
__launch_bounds__(NTHR)
__global__ void odernn_main(const float* __restrict__ data, const float* __restrict__ tsg,
                            const float* __restrict__ bu1, const float* __restrict__ bu2,
                            const float* __restrict__ br1, const float* __restrict__ br2,
                            const float* __restrict__ bn1, const float* __restrict__ bn2,
                            const float* __restrict__ bo1, const float* __restrict__ bo2,
                            const float* __restrict__ Wt1, const float* __restrict__ bt1,
                            const float* __restrict__ Wt2, const float* __restrict__ bt2,
                            const unsigned short* __restrict__ W,
                            float* __restrict__ out)
{
    __shared__ unsigned short cat[ROWS][CATP];   // y|s|x (bf16); later c2|x
    __shared__ unsigned short hur[ROWS][HURP];   // h_o / hu|hr / hn (overlaid)
    __shared__ float yf [ROWS][LATN];
    __shared__ float sf [ROWS][LATN];
    __shared__ float yof[ROWS][LATN];
    __shared__ float uf [ROWS][LATN];
    __shared__ float z1s[ROWS][100];
    __shared__ float msum[2][ROWS];
    __shared__ float bL[3072];                   // staged biases

    const int tid  = threadIdx.x;
    const int lane = tid & 63;
    const int w    = tid >> 6;       // wave 0..15
    const int arow = lane & 15;
    const int ah   = lane >> 4;
    const int r0   = blockIdx.x * ROWS;
    // Blocks sharing an XCD (bid % 8) get distinct rotations (bid >> 3).
    const int rot  = (blockIdx.x >> 3) & 15;     // in [0,16)
    const int rot8 = rot & 7;                    // for NS=8

    // ---- prologue: state zero, bias stage, x_0 ----
    for (int i = tid; i < ROWS * LATN; i += NTHR) {
        yf[i >> 8][i & 255] = 0.f;
        sf[i >> 8][i & 255] = 0.f;
    }
    for (int i = tid; i < ROWS * 512; i += NTHR)
        cat[i >> 9][i & 511] = 0;
    for (int i = tid; i < 3072; i += NTHR) {
        float v;
        if      (i <  256) v = bo1[i];
        else if (i <  512) v = bo2[i - 256];
        else if (i < 1024) v = bu1[i - 512];
        else if (i < 1536) v = br1[i - 1024];
        else if (i < 1792) v = bu2[i - 1536];
        else if (i < 2048) v = br2[i - 1792];
        else if (i < 2560) v = bn1[i - 2048];
        else               v = bn2[i - 2560];
        bL[i] = v;
    }
    // x-load: wave w owns row w; lane covers 2 cols
    const int xc = lane * 2;
    {
        const float2 xv = *(const float2*)(data + ((size_t)(r0 + w) * NTS + 199) * DIN + xc);
        cat[w][512 + xc + 0] = f2bf(xv.x);
        cat[w][512 + xc + 1] = f2bf(xv.y);
        float mp = (xc >= 64) ? (xv.x + xv.y) : 0.f;
#pragma unroll
        for (int m = 32; m >= 1; m >>= 1) mp += __shfl_xor(mp, m, 64);
        if (lane == 0) msum[0][w] = mp;
    }
    __syncthreads();

    for (int t = 0; t < NTS; ++t) {
        const float dtv = (t == 0) ? -0.01f : (tsg[199 - t] - tsg[200 - t]);

        // ---- G_o1: h_o = tanh(y @ Wo1 + bo1) -> hur[:,0:256] ----
        // wave covers cols [w*16, w*16+16): cb = w, NS=8, NFR=1
        {
            f4v a[1];
            float b = bL[w * 16 + arow];
            a[0] = (f4v){b, b, b, b};
            mmloop<256, 1>(&cat[0][0], CATP, W + OFF_WO1 + w * 8 * 512 + lane * 8, rot8, a, arow, ah);
#pragma unroll
            for (int i = 0; i < 4; ++i) {
                int row = ah * 4 + i, col = w * 16 + arow;
                hur[row][col] = f2bf(fast_tanh(a[0][i]));
            }
        }
        __syncthreads();

        // ---- G_o2: y_ode = y + (h_o @ Wo2 + bo2)*dt ----
        {
            f4v a[1];
            float b = bL[256 + w * 16 + arow];
            a[0] = (f4v){b, b, b, b};
            mmloop<256, 1>(&hur[0][0], HURP, W + OFF_WO2 + w * 8 * 512 + lane * 8, rot8, a, arow, ah);
#pragma unroll
            for (int i = 0; i < 4; ++i) {
                int row = ah * 4 + i, col = w * 16 + arow;
                float yo = yf[row][col] + a[0][i] * dtv;
                yof[row][col] = yo;
                cat[row][col] = f2bf(yo);
            }
        }
        __syncthreads();

        // ---- G_ur1: [hu|hr] = tanh(yc @ [Wu1|Wr1] + b), 2 passes of 32 cols ----
        // pass p: cols w*64 + p*32; cb = w*4 + p*2, NS=20
#pragma unroll 1
        for (int p = 0; p < 2; ++p) {
            f4v a[2];
#pragma unroll
            for (int f = 0; f < 2; ++f) {
                float b = bL[512 + w * 64 + p * 32 + f * 16 + arow];
                a[f] = (f4v){b, b, b, b};
            }
            mmloop<640, 2>(&cat[0][0], CATP,
                           W + OFF_WUR1 + (w * 4 + p * 2) * 20 * 512 + lane * 8, rot, a, arow, ah);
#pragma unroll
            for (int f = 0; f < 2; ++f)
#pragma unroll
                for (int i = 0; i < 4; ++i) {
                    int row = ah * 4 + i, col = w * 64 + p * 32 + f * 16 + arow;
                    hur[row][col] = f2bf(fast_tanh(a[f][i]));
                }
        }
        __syncthreads();

        // ---- G_ur2 + fused c2: u (waves 0-7), r -> c2 writes (waves 8-15) ----
        // col base c0 = w*32 (uniform), cb0 = w*2, NS=16, NFR=2
        {
            f4v a[2];
            const int c0 = w * 32;
#pragma unroll
            for (int f = 0; f < 2; ++f) {
                float b = bL[1536 + c0 + f * 16 + arow];
                a[f] = (f4v){b, b, b, b};
            }
            const int aoff = (w < 8) ? 0 : 512;
            mmloop<512, 2>(&hur[0][0] + aoff, HURP, W + OFF_WUR2 + (w * 2) * 16 * 512 + lane * 8, rot, a, arow, ah);
#pragma unroll
            for (int f = 0; f < 2; ++f)
#pragma unroll
                for (int i = 0; i < 4; ++i) {
                    int row = ah * 4 + i, j = c0 + f * 16 + arow;
                    float sg = fast_sig(a[f][i]);
                    if (j < 256) uf[row][j] = sg;
                    else {
                        int c = j - 256;
                        float yo = yof[row][c], so = sf[row][c];
                        cat[row][c]       = f2bf(yo * sg);
                        cat[row][256 + c] = f2bf(so * sg);
                    }
                }
        }
        __syncthreads();

        // ---- G_n1: hn = tanh(c2 @ Wn1 + bn1) -> hur[:,0:512]; issue x_{t+1} load ----
        // wave covers cols [w*32, w*32+32): cb0 = w*2, NS=20, NFR=2
        float2 xv;
        const bool hasx = (t + 1 < NTS);
        if (hasx)
            xv = *(const float2*)(data + ((size_t)(r0 + w) * NTS + (198 - t)) * DIN + xc);
        {
            f4v a[2];
#pragma unroll
            for (int f = 0; f < 2; ++f) {
                float b = bL[2048 + w * 32 + f * 16 + arow];
                a[f] = (f4v){b, b, b, b};
            }
            mmloop<640, 2>(&cat[0][0], CATP, W + OFF_WN1 + (w * 2) * 20 * 512 + lane * 8, rot, a, arow, ah);
#pragma unroll
            for (int f = 0; f < 2; ++f)
#pragma unroll
                for (int i = 0; i < 4; ++i) {
                    int row = ah * 4 + i, col = w * 32 + f * 16 + arow;
                    hur[row][col] = f2bf(fast_tanh(a[f][i]));
                }
        }
        __syncthreads();

        // ---- G_n2: ns = hn @ Wn2 + bn2 ; state update; write x_{t+1} ----
        // wave covers cols [w*32, w*32+32): cb0 = w*2, NS=16, NFR=2
        {
            f4v a[2];
#pragma unroll
            for (int f = 0; f < 2; ++f) {
                float b = bL[2560 + w * 32 + f * 16 + arow];
                a[f] = (f4v){b, b, b, b};
            }
            mmloop<512, 2>(&hur[0][0], HURP, W + OFF_WN2 + (w * 2) * 16 * 512 + lane * 8, rot, a, arow, ah);
#pragma unroll
            for (int f = 0; f < 2; ++f)
#pragma unroll
                for (int i = 0; i < 4; ++i) {
                    int row = ah * 4 + i, j = w * 32 + f * 16 + arow;
                    float val = a[f][i];
                    bool m = msum[t & 1][row] > 0.f;
                    if (j < 256) {
                        float u  = uf[row][j];
                        float yo = yof[row][j];
                        float ny = (1.f - u) * val + u * yo;
                        float yn = m ? ny : yo;
                        yf[row][j] = yn;
                        cat[row][j] = f2bf(yn);
                    } else {
                        int c = j - 256;
                        float u  = uf[row][c];
                        float so = sf[row][c];
                        float nstd = (1.f - u) * fabsf(val) + u * so;
                        float sn = m ? nstd : so;
                        sn = fabsf(sn);
                        sf[row][c] = sn;
                        cat[row][256 + c] = f2bf(sn);
                    }
                }
        }
        if (hasx) {
            cat[w][512 + xc + 0] = f2bf(xv.x);
            cat[w][512 + xc + 1] = f2bf(xv.y);
            float mp = (xc >= 64) ? (xv.x + xv.y) : 0.f;
#pragma unroll
            for (int m = 32; m >= 1; m >>= 1) mp += __shfl_xor(mp, m, 64);
            if (lane == 0) msum[(t + 1) & 1][w] = mp;
        }
        __syncthreads();
    }

    // ---- final head (fp32, once): z = tanh([y|s]@Wt1+bt1)@Wt2+bt2 ----
    for (int it = tid; it < ROWS * 100; it += NTHR) {
        int r = it / 100, j = it - r * 100;
        float acc = bt1[j];
        for (int k = 0; k < 256; ++k) acc += yf[r][k] * Wt1[k * 100 + j];
        for (int k = 0; k < 256; ++k) acc += sf[r][k] * Wt1[(256 + k) * 100 + j];
        z1s[r][j] = fast_tanh(acc);
    }
    __syncthreads();
    for (int it = tid; it < ROWS * 512; it += NTHR) {
        int r = it >> 9, j = it & 511;
        float acc = bt2[j];
        for (int k = 0; k < 100; ++k) acc += z1s[r][k] * Wt2[k * 512 + j];
        int bg = r0 + r;
        if (j < 256) {
            out[(size_t)bg * 256 + j] = acc;
        } else {
            float v = fabsf(acc);
            if (v < 1e-20f) v = 1e-20f;
            out[(size_t)B_TOT * 256 + (size_t)bg * 256 + (j - 256)] = v;
        }
    }
}

extern "C" void kernel_launch(void* const* d_in, const int* in_sizes, int n_in,
                              void* d_out, int out_size, void* d_ws, size_t ws_size,
                              hipStream_t stream) {
    const float* data = (const float*)d_in[0];
    const float* ts   = (const float*)d_in[1];
    const float* Wu1  = (const float*)d_in[2];
    const float* bu1  = (const float*)d_in[3];
    const float* Wu2  = (const float*)d_in[4];
    const float* bu2  = (const float*)d_in[5];
    const float* Wr1  = (const float*)d_in[6];
    const float* br1  = (const float*)d_in[7];
    const float* Wr2  = (const float*)d_in[8];
    const float* br2  = (const float*)d_in[9];
    const float* Wn1  = (const float*)d_in[10];
    const float* bn1  = (const float*)d_in[11];
    const float* Wn2  = (const float*)d_in[12];
    const float* bn2  = (const float*)d_in[13];
    const float* Wo1  = (const float*)d_in[14];
    const float* bo1  = (const float*)d_in[15];
    const float* Wo2  = (const float*)d_in[16];
    const float* bo2  = (const float*)d_in[17];
    const float* Wt1  = (const float*)d_in[18];
    const float* bt1  = (const float*)d_in[19];
    const float* Wt2  = (const float*)d_in[20];
    const float* bt2  = (const float*)d_in[21];
    unsigned short* ws = (unsigned short*)d_ws;
    float* out = (float*)d_out;

    prep_weights<<<(WS_ELEMS + 255) / 256, 256, 0, stream>>>(
        Wu1, Wr1, Wu2, Wr2, Wn1, Wn2, Wo1, Wo2, ws);
    odernn_main<<<NBLK, NTHR, 0, stream>>>(
        data, ts, bu1, bu2, br1, br2, bn1, bn2, bo1, bo2,
        Wt1, bt1, Wt2, bt2, ws, out);
}